// Round 1
// baseline (572.984 us; speedup 1.0000x reference)
//
#include <hip/hip_runtime.h>
#include <math.h>

#define NB 8
#define LQ 1024
#define LK 1024
#define DMODEL 512
#define NH 8
#define HD 64
#define R_TOT (NB * LQ)   // 8192 rows

// ---------------- GEMM: C[M,N] = act(X[M,K] @ W[N,K]^T + bias) ----------------
#define BM 64
#define BN 64
#define BK 32
#define LP 68   // padded row length for [BK][BM] LDS tiles (68*4B = 16B-aligned rows)

__global__ __launch_bounds__(256)
void gemm_nt(const float* __restrict__ X, const float* __restrict__ W,
             const float* __restrict__ bias, float* __restrict__ C,
             int M, int N, int K, int relu)
{
    __shared__ float As[BK][LP];   // As[k][m]
    __shared__ float Bs[BK][LP];   // Bs[k][n]
    const int tid = threadIdx.x;
    const int tx = tid & 15, ty = tid >> 4;
    const int n0 = blockIdx.x * BN;
    const int m0 = blockIdx.y * BM;

    float acc[4][4] = {};

    for (int k0 = 0; k0 < K; k0 += BK) {
        // stage A and B tiles, transposed to k-major
        #pragma unroll
        for (int it = 0; it < 2; ++it) {
            int f   = tid + it * 256;    // 0..511
            int row = f >> 3;            // 0..63
            int c4  = f & 7;             // 0..7
            float4 a = *(const float4*)(X + (size_t)(m0 + row) * K + k0 + c4 * 4);
            As[c4*4+0][row] = a.x; As[c4*4+1][row] = a.y;
            As[c4*4+2][row] = a.z; As[c4*4+3][row] = a.w;
            float4 b = *(const float4*)(W + (size_t)(n0 + row) * K + k0 + c4 * 4);
            Bs[c4*4+0][row] = b.x; Bs[c4*4+1][row] = b.y;
            Bs[c4*4+2][row] = b.z; Bs[c4*4+3][row] = b.w;
        }
        __syncthreads();
        #pragma unroll
        for (int kk = 0; kk < BK; ++kk) {
            float4 a = *(const float4*)&As[kk][4*ty];
            float4 b = *(const float4*)&Bs[kk][4*tx];
            float av[4] = {a.x, a.y, a.z, a.w};
            float bv[4] = {b.x, b.y, b.z, b.w};
            #pragma unroll
            for (int i = 0; i < 4; ++i)
                #pragma unroll
                for (int j = 0; j < 4; ++j)
                    acc[i][j] += av[i] * bv[j];
        }
        __syncthreads();
    }

    #pragma unroll
    for (int i = 0; i < 4; ++i) {
        int m = m0 + 4*ty + i;
        #pragma unroll
        for (int j = 0; j < 4; ++j) {
            int n = n0 + 4*tx + j;
            float vv = acc[i][j];
            if (bias) vv += bias[n];
            if (relu) vv = fmaxf(vv, 0.0f);
            C[(size_t)m * N + n] = vv;
        }
    }
}

// ---------------- Flash attention, fp32 ----------------
// grid: (LQ/64, NH, NB), block 256.  Each block: 64 q-rows of one (b,h).
#define TQ 64
#define TK 64
#define AP 68

__global__ __launch_bounds__(256)
void attn_kernel(const float* __restrict__ qp, const float* __restrict__ kp,
                 const float* __restrict__ vp, const int* __restrict__ mask,
                 float* __restrict__ attn)
{
    __shared__ float Qs[HD][AP];  // [d][q]  (scaled)
    __shared__ float Ks[HD][AP];  // [d][k]
    __shared__ float Vs[TK][AP];  // [k][d]
    __shared__ float Ps[TK][AP];  // [k][q]  (P transposed)
    __shared__ float mk[TK];

    const int tid = threadIdx.x;
    const int tx = tid & 15, ty = tid >> 4;
    const int q0 = blockIdx.x * TQ;
    const int h  = blockIdx.y;
    const int b  = blockIdx.z;
    const size_t base = ((size_t)b * LQ) * DMODEL + (size_t)h * HD;
    const float sc = 0.044194173824159216f;   // 1/sqrt(512)  (module scales by dim_out!)

    // load Q tile transposed, scaled
    #pragma unroll
    for (int it = 0; it < 4; ++it) {
        int f   = tid + it * 256;  // 0..1023
        int row = f >> 4;          // 0..63
        int c4  = f & 15;          // 0..15
        float4 a = *(const float4*)(qp + base + (size_t)(q0 + row) * DMODEL + c4 * 4);
        Qs[c4*4+0][row] = a.x * sc; Qs[c4*4+1][row] = a.y * sc;
        Qs[c4*4+2][row] = a.z * sc; Qs[c4*4+3][row] = a.w * sc;
    }

    float m_[4], l_[4], o_[4][4];
    #pragma unroll
    for (int i = 0; i < 4; ++i) {
        m_[i] = -1.0e30f; l_[i] = 0.0f;
        #pragma unroll
        for (int j = 0; j < 4; ++j) o_[i][j] = 0.0f;
    }

    for (int k0 = 0; k0 < LK; k0 += TK) {
        // stage K (transposed), V (natural), mask
        #pragma unroll
        for (int it = 0; it < 4; ++it) {
            int f   = tid + it * 256;
            int row = f >> 4;
            int c4  = f & 15;
            float4 a = *(const float4*)(kp + base + (size_t)(k0 + row) * DMODEL + c4 * 4);
            Ks[c4*4+0][row] = a.x; Ks[c4*4+1][row] = a.y;
            Ks[c4*4+2][row] = a.z; Ks[c4*4+3][row] = a.w;
            float4 v = *(const float4*)(vp + base + (size_t)(k0 + row) * DMODEL + c4 * 4);
            *(float4*)&Vs[row][c4*4] = v;
        }
        if (tid < TK) mk[tid] = mask[b * LK + k0 + tid] ? -1.0e30f : 0.0f;
        __syncthreads();

        // S tile: s[i][j] = Q[q0+4ty+i] . K[k0+4tx+j]
        float s[4][4] = {};
        #pragma unroll 8
        for (int d = 0; d < HD; ++d) {
            float4 a = *(const float4*)&Qs[d][4*ty];
            float4 bq = *(const float4*)&Ks[d][4*tx];
            float av[4] = {a.x, a.y, a.z, a.w};
            float bv[4] = {bq.x, bq.y, bq.z, bq.w};
            #pragma unroll
            for (int i = 0; i < 4; ++i)
                #pragma unroll
                for (int j = 0; j < 4; ++j)
                    s[i][j] += av[i] * bv[j];
        }
        #pragma unroll
        for (int i = 0; i < 4; ++i)
            #pragma unroll
            for (int j = 0; j < 4; ++j)
                s[i][j] += mk[4*tx + j];

        // online softmax per q-row (16 lanes per row share state)
        #pragma unroll
        for (int i = 0; i < 4; ++i) {
            float rmax = fmaxf(fmaxf(s[i][0], s[i][1]), fmaxf(s[i][2], s[i][3]));
            #pragma unroll
            for (int off = 1; off < 16; off <<= 1)
                rmax = fmaxf(rmax, __shfl_xor(rmax, off));
            float mnew  = fmaxf(m_[i], rmax);
            float alpha = __expf(m_[i] - mnew);
            float p[4], rsum = 0.0f;
            #pragma unroll
            for (int j = 0; j < 4; ++j) { p[j] = __expf(s[i][j] - mnew); rsum += p[j]; }
            #pragma unroll
            for (int off = 1; off < 16; off <<= 1)
                rsum += __shfl_xor(rsum, off);
            l_[i] = l_[i] * alpha + rsum;
            m_[i] = mnew;
            #pragma unroll
            for (int j = 0; j < 4; ++j) o_[i][j] *= alpha;
            #pragma unroll
            for (int j = 0; j < 4; ++j) Ps[4*tx + j][4*ty + i] = p[j];
        }
        __syncthreads();

        // PV: o[i][j] += sum_kk P[4ty+i][kk] * V[kk][4tx+j]
        #pragma unroll 8
        for (int kk = 0; kk < TK; ++kk) {
            float4 pv = *(const float4*)&Ps[kk][4*ty];
            float4 vv = *(const float4*)&Vs[kk][4*tx];
            float pa[4] = {pv.x, pv.y, pv.z, pv.w};
            float va[4] = {vv.x, vv.y, vv.z, vv.w};
            #pragma unroll
            for (int i = 0; i < 4; ++i)
                #pragma unroll
                for (int j = 0; j < 4; ++j)
                    o_[i][j] += pa[i] * va[j];
        }
        __syncthreads();
    }

    // write out: attn[b, q0+4ty+i, h*64 + 4tx+j]
    #pragma unroll
    for (int i = 0; i < 4; ++i) {
        float inv = (m_[i] > -1.0e29f) ? (1.0f / l_[i]) : 0.0f;  // all-masked row -> 0 (ref: NaN->0)
        #pragma unroll
        for (int j = 0; j < 4; ++j)
            attn[base + (size_t)(q0 + 4*ty + i) * DMODEL + 4*tx + j] = o_[i][j] * inv;
    }
}

// ---------------- fused add + LayerNorm: out = LN(A+B)*g + beta ----------------
__global__ __launch_bounds__(256)
void add_ln(const float* __restrict__ A, const float* __restrict__ Bv,
            const float* __restrict__ g, const float* __restrict__ beta,
            float* __restrict__ out)
{
    const int row = blockIdx.x;
    const int tid = threadIdx.x;
    const size_t off = (size_t)row * DMODEL;
    float x0 = A[off + tid]       + Bv[off + tid];
    float x1 = A[off + tid + 256] + Bv[off + tid + 256];
    float s  = x0 + x1;
    float sq = x0 * x0 + x1 * x1;
    #pragma unroll
    for (int o = 1; o < 64; o <<= 1) {
        s  += __shfl_xor(s,  o);
        sq += __shfl_xor(sq, o);
    }
    __shared__ float ls[4], lq[4];
    const int w = tid >> 6;
    if ((tid & 63) == 0) { ls[w] = s; lq[w] = sq; }
    __syncthreads();
    s  = ls[0] + ls[1] + ls[2] + ls[3];
    sq = lq[0] + lq[1] + lq[2] + lq[3];
    const float mean = s * (1.0f / DMODEL);
    const float var  = sq * (1.0f / DMODEL) - mean * mean;
    const float r    = rsqrtf(var + 1e-5f);
    out[off + tid]       = (x0 - mean) * r * g[tid]       + beta[tid];
    out[off + tid + 256] = (x1 - mean) * r * g[tid + 256] + beta[tid + 256];
}

// ---------------- launch ----------------
extern "C" void kernel_launch(void* const* d_in, const int* in_sizes, int n_in,
                              void* d_out, int out_size, void* d_ws, size_t ws_size,
                              hipStream_t stream)
{
    const float* q    = (const float*)d_in[0];
    const float* k    = (const float*)d_in[1];
    const float* v    = (const float*)d_in[2];
    const int*   mask = (const int*)  d_in[3];
    const float* Wq   = (const float*)d_in[4];
    const float* Wk   = (const float*)d_in[5];
    const float* Wv   = (const float*)d_in[6];
    const float* Wo   = (const float*)d_in[7];
    const float* bo   = (const float*)d_in[8];
    const float* g1   = (const float*)d_in[9];
    const float* b1   = (const float*)d_in[10];
    const float* g2   = (const float*)d_in[11];
    const float* b2   = (const float*)d_in[12];
    float* out = (float*)d_out;

    const size_t SLOT = (size_t)R_TOT * DMODEL;   // 4 Mi floats
    float* ws = (float*)d_ws;
    float* qp = ws;                // slot 0
    float* kp = ws + SLOT;         // slot 1
    float* vp = ws + 2 * SLOT;     // slot 2
    float* at = ws + 3 * SLOT;     // slot 3
    float* y  = kp;                // reuse: kp dead after attention
    float* z  = vp;                // reuse: vp dead after attention

    dim3 gg(DMODEL / BN, R_TOT / BM);   // (8, 128)
    gemm_nt<<<gg, 256, 0, stream>>>(q, Wq, nullptr, qp, R_TOT, DMODEL, DMODEL, 0);
    gemm_nt<<<gg, 256, 0, stream>>>(k, Wk, nullptr, kp, R_TOT, DMODEL, DMODEL, 0);
    gemm_nt<<<gg, 256, 0, stream>>>(v, Wv, nullptr, vp, R_TOT, DMODEL, DMODEL, 0);

    attn_kernel<<<dim3(LQ / TQ, NH, NB), 256, 0, stream>>>(qp, kp, vp, mask, at);

    add_ln<<<R_TOT, 256, 0, stream>>>(qp, at, g1, b1, y);

    gemm_nt<<<gg, 256, 0, stream>>>(y, Wo, bo, z, R_TOT, DMODEL, DMODEL, 1);

    add_ln<<<R_TOT, 256, 0, stream>>>(y, z, g2, b2, out);
}

// Round 2
// 219.509 us; speedup vs baseline: 2.6103x; 2.6103x over previous
//
#include <hip/hip_runtime.h>
#include <math.h>
#include <stdint.h>

#define NB 8
#define SEQ 1024
#define DMODEL 512
#define NH 8
#define HD 64
#define R_TOT (NB * SEQ)   // 8192 rows

typedef __attribute__((ext_vector_type(8))) short bf16x8;
typedef __attribute__((ext_vector_type(4))) float f32x4;

__device__ __forceinline__ short f2b(float x) {
    uint32_t u = __float_as_uint(x);
    u += 0x7FFF + ((u >> 16) & 1);          // round-to-nearest-even
    return (short)(u >> 16);
}
__device__ __forceinline__ float b2f(short s) {
    return __uint_as_float(((uint32_t)(uint16_t)s) << 16);
}

#define GLD_LDS16(g, l)                                                        \
    __builtin_amdgcn_global_load_lds(                                          \
        (const __attribute__((address_space(1))) uint32_t*)(g),                \
        (__attribute__((address_space(3))) uint32_t*)(l), 16, 0, 0)

// ---------------- fp32 -> bf16 convert ----------------
__global__ __launch_bounds__(256)
void cvt_bf16(const float* __restrict__ src, short* __restrict__ dst, int n4)
{
    int i = blockIdx.x * 256 + threadIdx.x;
    if (i >= n4) return;
    float4 v = ((const float4*)src)[i];
    short4 o;
    o.x = f2b(v.x); o.y = f2b(v.y); o.z = f2b(v.z); o.w = f2b(v.w);
    ((short4*)dst)[i] = o;
}

// ---------------- bf16 MFMA GEMM:  C[M,N] = act(A[M,K] @ W[N,K]^T + bias) ----------------
// tile 128x64, BK=32, 4 waves as 2x2 (wave-tile 64x32)
#define GBM 128
#define GBN 64
#define GBK 32

__global__ __launch_bounds__(256)
void gemm_bf16(const short* __restrict__ A, const short* __restrict__ Bm,
               const float* __restrict__ bias, short* __restrict__ C,
               int M, int N, int K, int relu)
{
    __shared__ short As[GBM * GBK];   // row-major [128][32]
    __shared__ short Bs[GBN * GBK];   // row-major [64][32]
    const int tid = threadIdx.x;
    const int l   = tid & 63, w = tid >> 6;
    const int l15 = l & 15,  l4 = l >> 4;
    const int wrow = w >> 1, wcol = w & 1;
    const int m0 = blockIdx.y * GBM, n0 = blockIdx.x * GBN;

    f32x4 acc[4][2] = {};

    for (int k0 = 0; k0 < K; k0 += GBK) {
        // stage A (2 chunks/thread) and B (1 chunk/thread) via async global->LDS
        {
            int ch = tid;
            GLD_LDS16(A + (size_t)(m0 + (ch >> 2)) * K + k0 + (ch & 3) * 8, &As[ch * 8]);
            ch = tid + 256;
            GLD_LDS16(A + (size_t)(m0 + (ch >> 2)) * K + k0 + (ch & 3) * 8, &As[ch * 8]);
            ch = tid;
            GLD_LDS16(Bm + (size_t)(n0 + (ch >> 2)) * K + k0 + (ch & 3) * 8, &Bs[ch * 8]);
        }
        __syncthreads();   // drains vmcnt before any wave reads LDS

        bf16x8 af[4], bfr[2];
        #pragma unroll
        for (int mi = 0; mi < 4; ++mi)
            af[mi] = *(const bf16x8*)&As[(wrow * 64 + mi * 16 + l15) * GBK + l4 * 8];
        #pragma unroll
        for (int ni = 0; ni < 2; ++ni)
            bfr[ni] = *(const bf16x8*)&Bs[(wcol * 32 + ni * 16 + l15) * GBK + l4 * 8];

        #pragma unroll
        for (int mi = 0; mi < 4; ++mi)
            #pragma unroll
            for (int ni = 0; ni < 2; ++ni)
                acc[mi][ni] = __builtin_amdgcn_mfma_f32_16x16x32_bf16(af[mi], bfr[ni], acc[mi][ni], 0, 0, 0);
        __syncthreads();
    }

    // epilogue: D layout row=(l>>4)*4+reg, col=l&15
    #pragma unroll
    for (int mi = 0; mi < 4; ++mi) {
        #pragma unroll
        for (int ni = 0; ni < 2; ++ni) {
            int col = n0 + wcol * 32 + ni * 16 + l15;
            float bb = bias ? bias[col] : 0.0f;
            #pragma unroll
            for (int r = 0; r < 4; ++r) {
                int row = m0 + wrow * 64 + mi * 16 + l4 * 4 + r;
                float vv = acc[mi][ni][r] + bb;
                if (relu) vv = fmaxf(vv, 0.0f);
                C[(size_t)row * N + col] = f2b(vv);
            }
        }
    }
}

// ---------------- bf16 MFMA flash attention ----------------
// grid (SEQ/64, NH, NB), 256 threads = 4 waves, wave w owns q-rows q0+w*16..+15
__global__ __launch_bounds__(256)
void attn_mfma(const short* __restrict__ qp, const short* __restrict__ kp,
               const short* __restrict__ vp, const int* __restrict__ mask,
               short* __restrict__ attn)
{
    __shared__ char VtB[64 * 128];   // Vt[d][key] bf16, XOR-swizzled rows
    __shared__ char PsB[4 * 2048];   // per-wave P[16q][64k] bf16, XOR-swizzled
    __shared__ float mk[64];

    const int tid = threadIdx.x;
    const int l   = tid & 63, w = tid >> 6;
    const int l15 = l & 15,  l4 = l >> 4;
    const int q0  = blockIdx.x * 64;
    const int h   = blockIdx.y, b = blockIdx.z;
    const size_t base = ((size_t)b * SEQ) * DMODEL + h * HD;
    const float sc = 0.044194173824159216f;   // 1/sqrt(512): module scales by dim_out

    // hoisted Q fragments (A-operand): lane holds Q[q0+w*16+l15][t*32 + l4*8 + i]
    bf16x8 qf[2];
    {
        const short* qrow = qp + base + (size_t)(q0 + w * 16 + l15) * DMODEL + l4 * 8;
        qf[0] = *(const bf16x8*)qrow;
        qf[1] = *(const bf16x8*)(qrow + 32);
    }

    float m_[4], l_[4];
    f32x4 oacc[4] = {};
    #pragma unroll
    for (int r = 0; r < 4; ++r) { m_[r] = -1.0e30f; l_[r] = 0.0f; }

    char* myPs = PsB + w * 2048;

    for (int k0 = 0; k0 < SEQ; k0 += 64) {
        // ---- stage V transposed + swizzled: Vt[d][key] ----
        #pragma unroll
        for (int it = 0; it < 2; ++it) {
            int f   = tid + it * 256;   // 0..511
            int key = f & 63;
            int c4  = f >> 6;           // 0..7
            bf16x8 vv = *(const bf16x8*)(vp + base + (size_t)(k0 + key) * DMODEL + c4 * 8);
            #pragma unroll
            for (int i = 0; i < 8; ++i) {
                int d = c4 * 8 + i;
                int addr = (d * 128 + key * 2) ^ ((d & 7) << 4);
                *(short*)(VtB + addr) = vv[i];
            }
        }
        if (tid < 64) mk[tid] = mask[b * SEQ + k0 + tid] ? -1.0e30f : 0.0f;
        __syncthreads();

        // ---- S = Q K^T (K frags straight from global; L1/L2 resident) ----
        f32x4 s[4];
        #pragma unroll
        for (int c = 0; c < 4; ++c) {
            const short* krow = kp + base + (size_t)(k0 + c * 16 + l15) * DMODEL + l4 * 8;
            bf16x8 kf0 = *(const bf16x8*)krow;
            bf16x8 kf1 = *(const bf16x8*)(krow + 32);
            f32x4 z = {};
            z = __builtin_amdgcn_mfma_f32_16x16x32_bf16(qf[0], kf0, z, 0, 0, 0);
            z = __builtin_amdgcn_mfma_f32_16x16x32_bf16(qf[1], kf1, z, 0, 0, 0);
            s[c] = z;
        }
        float mkv[4];
        #pragma unroll
        for (int c = 0; c < 4; ++c) mkv[c] = mk[c * 16 + l15];
        #pragma unroll
        for (int c = 0; c < 4; ++c)
            #pragma unroll
            for (int r = 0; r < 4; ++r)
                s[c][r] = s[c][r] * sc + mkv[c];

        // ---- online softmax; D-layout row = l4*4+r, 16 lanes (l15) share a row ----
        #pragma unroll
        for (int r = 0; r < 4; ++r) {
            float rmax = fmaxf(fmaxf(s[0][r], s[1][r]), fmaxf(s[2][r], s[3][r]));
            rmax = fmaxf(rmax, __shfl_xor(rmax, 1));
            rmax = fmaxf(rmax, __shfl_xor(rmax, 2));
            rmax = fmaxf(rmax, __shfl_xor(rmax, 4));
            rmax = fmaxf(rmax, __shfl_xor(rmax, 8));
            float mnew  = fmaxf(m_[r], rmax);
            float alpha = __expf(m_[r] - mnew);
            float rsum = 0.0f;
            short pb[4];
            #pragma unroll
            for (int c = 0; c < 4; ++c) {
                float p = __expf(s[c][r] - mnew);
                rsum += p;
                pb[c] = f2b(p);
            }
            rsum += __shfl_xor(rsum, 1);
            rsum += __shfl_xor(rsum, 2);
            rsum += __shfl_xor(rsum, 4);
            rsum += __shfl_xor(rsum, 8);
            l_[r] = l_[r] * alpha + rsum;
            m_[r] = mnew;
            #pragma unroll
            for (int dblk = 0; dblk < 4; ++dblk) oacc[dblk][r] *= alpha;
            // write P row to wave-private LDS (swizzled)
            int rowq = l4 * 4 + r;
            int sw   = (rowq & 7) << 4;
            #pragma unroll
            for (int c = 0; c < 4; ++c) {
                int addr = (rowq * 128 + (c * 16 + l15) * 2) ^ sw;
                *(short*)(myPs + addr) = pb[c];
            }
        }

        // ---- P frags (A-operand): lane holds P[l15][t*32 + l4*8 + i] ----
        bf16x8 pf[2];
        {
            int sw = (l15 & 7) << 4;
            pf[0] = *(const bf16x8*)(myPs + ((l15 * 128 + l4 * 16) ^ sw));
            pf[1] = *(const bf16x8*)(myPs + ((l15 * 128 + 64 + l4 * 16) ^ sw));
        }

        // ---- O += P V ----
        #pragma unroll
        for (int dblk = 0; dblk < 4; ++dblk) {
            int d  = dblk * 16 + l15;
            int sw = (d & 7) << 4;
            bf16x8 vf0 = *(const bf16x8*)(VtB + ((d * 128 + l4 * 16) ^ sw));
            bf16x8 vf1 = *(const bf16x8*)(VtB + ((d * 128 + 64 + l4 * 16) ^ sw));
            oacc[dblk] = __builtin_amdgcn_mfma_f32_16x16x32_bf16(pf[0], vf0, oacc[dblk], 0, 0, 0);
            oacc[dblk] = __builtin_amdgcn_mfma_f32_16x16x32_bf16(pf[1], vf1, oacc[dblk], 0, 0, 0);
        }
        __syncthreads();
    }

    #pragma unroll
    for (int r = 0; r < 4; ++r) {
        float inv = (m_[r] > -1.0e29f) ? 1.0f / l_[r] : 0.0f;   // all-masked row -> 0
        int row = q0 + w * 16 + l4 * 4 + r;
        #pragma unroll
        for (int dblk = 0; dblk < 4; ++dblk)
            attn[base + (size_t)row * DMODEL + dblk * 16 + l15] = f2b(oacc[dblk][r] * inv);
    }
}

// ---------------- fused add + LayerNorm (bf16 in, bf16 or fp32 out) ----------------
__global__ __launch_bounds__(256)
void add_ln_b(const short* __restrict__ A, const short* __restrict__ Bv,
              const float* __restrict__ g, const float* __restrict__ beta,
              short* __restrict__ outb, float* __restrict__ outf)
{
    const int row = blockIdx.x;
    const int tid = threadIdx.x;
    const size_t off = (size_t)row * DMODEL;
    short2 a2 = *(const short2*)&A[off + tid * 2];
    short2 c2 = *(const short2*)&Bv[off + tid * 2];
    float x0 = b2f(a2.x) + b2f(c2.x);
    float x1 = b2f(a2.y) + b2f(c2.y);
    float s  = x0 + x1;
    float sq = x0 * x0 + x1 * x1;
    #pragma unroll
    for (int o = 1; o < 64; o <<= 1) {
        s  += __shfl_xor(s,  o);
        sq += __shfl_xor(sq, o);
    }
    __shared__ float ls[4], lq[4];
    const int w = tid >> 6;
    if ((tid & 63) == 0) { ls[w] = s; lq[w] = sq; }
    __syncthreads();
    s  = ls[0] + ls[1] + ls[2] + ls[3];
    sq = lq[0] + lq[1] + lq[2] + lq[3];
    const float mean = s * (1.0f / DMODEL);
    const float var  = sq * (1.0f / DMODEL) - mean * mean;
    const float rs   = rsqrtf(var + 1e-5f);
    const int c0 = tid * 2, c1 = tid * 2 + 1;
    float y0 = (x0 - mean) * rs * g[c0] + beta[c0];
    float y1 = (x1 - mean) * rs * g[c1] + beta[c1];
    if (outb) {
        short2 o; o.x = f2b(y0); o.y = f2b(y1);
        *(short2*)&outb[off + tid * 2] = o;
    } else {
        float2 o; o.x = y0; o.y = y1;
        *(float2*)&outf[off + tid * 2] = o;
    }
}

// ---------------- launch ----------------
extern "C" void kernel_launch(void* const* d_in, const int* in_sizes, int n_in,
                              void* d_out, int out_size, void* d_ws, size_t ws_size,
                              hipStream_t stream)
{
    const float* q    = (const float*)d_in[0];
    const float* k    = (const float*)d_in[1];
    const float* v    = (const float*)d_in[2];
    const int*   mask = (const int*)  d_in[3];
    const float* Wq   = (const float*)d_in[4];
    const float* Wk   = (const float*)d_in[5];
    const float* Wv   = (const float*)d_in[6];
    const float* Wo   = (const float*)d_in[7];
    const float* bo   = (const float*)d_in[8];
    const float* g1   = (const float*)d_in[9];
    const float* b1   = (const float*)d_in[10];
    const float* g2   = (const float*)d_in[11];
    const float* bt2  = (const float*)d_in[12];
    float* out = (float*)d_out;

    short* ws = (short*)d_ws;
    const size_t WSZ  = (size_t)DMODEL * DMODEL;   // 256K elems
    const size_t SLOT = (size_t)R_TOT * DMODEL;    // 4M elems
    short* wq  = ws;
    short* wk  = ws + WSZ;
    short* wv  = ws + 2 * WSZ;
    short* wo  = ws + 3 * WSZ;
    short* qb  = ws + 4 * WSZ;
    short* kb  = qb + SLOT;
    short* vb  = kb + SLOT;
    short* qpb = vb + SLOT;
    short* kpb = qpb + SLOT;
    short* vpb = kpb + SLOT;
    short* at  = qb;   // qb dead after its GEMM
    short* y   = kb;   // kb dead after its GEMM
    short* z   = vb;   // vb dead after its GEMM

    const int n4b = (int)(SLOT / 4);   // 1M float4 chunks
    const int n4w = (int)(WSZ / 4);    // 64K
    cvt_bf16<<<n4b / 256, 256, 0, stream>>>(q, qb, n4b);
    cvt_bf16<<<n4b / 256, 256, 0, stream>>>(k, kb, n4b);
    cvt_bf16<<<n4b / 256, 256, 0, stream>>>(v, vb, n4b);
    cvt_bf16<<<n4w / 256, 256, 0, stream>>>(Wq, wq, n4w);
    cvt_bf16<<<n4w / 256, 256, 0, stream>>>(Wk, wk, n4w);
    cvt_bf16<<<n4w / 256, 256, 0, stream>>>(Wv, wv, n4w);
    cvt_bf16<<<n4w / 256, 256, 0, stream>>>(Wo, wo, n4w);

    dim3 gg(DMODEL / GBN, R_TOT / GBM);   // (8, 64)
    gemm_bf16<<<gg, 256, 0, stream>>>(qb, wq, nullptr, qpb, R_TOT, DMODEL, DMODEL, 0);
    gemm_bf16<<<gg, 256, 0, stream>>>(kb, wk, nullptr, kpb, R_TOT, DMODEL, DMODEL, 0);
    gemm_bf16<<<gg, 256, 0, stream>>>(vb, wv, nullptr, vpb, R_TOT, DMODEL, DMODEL, 0);

    attn_mfma<<<dim3(SEQ / 64, NH, NB), 256, 0, stream>>>(qpb, kpb, vpb, mask, at);

    add_ln_b<<<R_TOT, 256, 0, stream>>>(qpb, at, g1, b1, y, nullptr);

    gemm_bf16<<<gg, 256, 0, stream>>>(y, wo, bo, z, R_TOT, DMODEL, DMODEL, 1);

    add_ln_b<<<R_TOT, 256, 0, stream>>>(y, z, g2, bt2, nullptr, out);
}

// Round 3
// 213.249 us; speedup vs baseline: 2.6869x; 1.0294x over previous
//
#include <hip/hip_runtime.h>
#include <math.h>
#include <stdint.h>

#define NB 8
#define SEQ 1024
#define DMODEL 512
#define NH 8
#define HD 64
#define R_TOT (NB * SEQ)   // 8192 rows

typedef __attribute__((ext_vector_type(8))) short bf16x8;
typedef __attribute__((ext_vector_type(4))) float f32x4;

__device__ __forceinline__ short f2b(float x) {
    uint32_t u = __float_as_uint(x);
    u += 0x7FFF + ((u >> 16) & 1);          // round-to-nearest-even
    return (short)(u >> 16);
}
__device__ __forceinline__ float b2f(short s) {
    return __uint_as_float(((uint32_t)(uint16_t)s) << 16);
}

#define GLD_LDS16(g, l)                                                        \
    __builtin_amdgcn_global_load_lds(                                          \
        (const __attribute__((address_space(1))) uint32_t*)(g),                \
        (__attribute__((address_space(3))) uint32_t*)(l), 16, 0, 0)

// ---------------- merged fp32 -> bf16 convert (q,k,v + 4 weights in 1 launch) ----------------
#define N4B (R_TOT * DMODEL / 4)    // 1048576 float4 per activation tensor
#define N4W (DMODEL * DMODEL / 4)   // 65536 per weight

__global__ __launch_bounds__(256)
void cvt_all(const float* __restrict__ q, const float* __restrict__ k, const float* __restrict__ v,
             const float* __restrict__ wq, const float* __restrict__ wk,
             const float* __restrict__ wv, const float* __restrict__ wo,
             short* dq, short* dk, short* dv, short* dwq, short* dwk, short* dwv, short* dwo)
{
    long i = (long)blockIdx.x * 256 + threadIdx.x;
    const float* s; short* d; long off;
    if (i < (long)N4B)          { s = q;  d = dq;  off = i; }
    else if (i < 2L * N4B)      { s = k;  d = dk;  off = i - N4B; }
    else if (i < 3L * N4B)      { s = v;  d = dv;  off = i - 2L * N4B; }
    else {
        long j = i - 3L * N4B;
        int  w = (int)(j >> 16);           // j / N4W
        off = j & (N4W - 1);
        s = (w == 0) ? wq : (w == 1) ? wk : (w == 2) ? wv : wo;
        d = (w == 0) ? dwq : (w == 1) ? dwk : (w == 2) ? dwv : dwo;
    }
    float4 x = ((const float4*)s)[off];
    short4 o;
    o.x = f2b(x.x); o.y = f2b(x.y); o.z = f2b(x.z); o.w = f2b(x.w);
    ((short4*)d)[off] = o;
}

// ---------------- bf16 MFMA GEMM:  C[M,N] = act(A[M,K] @ B[N,K]^T + bias), batched ----------------
#define GBM 128
#define GBN 64
#define GBK 32

__global__ __launch_bounds__(256)
void gemm_bf16(const short* __restrict__ A, const short* __restrict__ Bm,
               const float* __restrict__ bias, short* __restrict__ C,
               int M, int N, int K, int relu,
               long sAb, long sBb, long sCb)
{
    __shared__ short As[GBM * GBK];
    __shared__ short Bs[GBN * GBK];
    const int tid = threadIdx.x;
    const int l   = tid & 63, w = tid >> 6;
    const int l15 = l & 15,  l4 = l >> 4;
    const int wrow = w >> 1, wcol = w & 1;
    const int m0 = blockIdx.y * GBM, n0 = blockIdx.x * GBN;
    A  += (long)blockIdx.z * sAb;
    Bm += (long)blockIdx.z * sBb;
    C  += (long)blockIdx.z * sCb;

    f32x4 acc[4][2] = {};

    for (int k0 = 0; k0 < K; k0 += GBK) {
        {
            int ch = tid;
            GLD_LDS16(A + (size_t)(m0 + (ch >> 2)) * K + k0 + (ch & 3) * 8, &As[ch * 8]);
            ch = tid + 256;
            GLD_LDS16(A + (size_t)(m0 + (ch >> 2)) * K + k0 + (ch & 3) * 8, &As[ch * 8]);
            ch = tid;
            GLD_LDS16(Bm + (size_t)(n0 + (ch >> 2)) * K + k0 + (ch & 3) * 8, &Bs[ch * 8]);
        }
        __syncthreads();

        bf16x8 af[4], bfr[2];
        #pragma unroll
        for (int mi = 0; mi < 4; ++mi)
            af[mi] = *(const bf16x8*)&As[(wrow * 64 + mi * 16 + l15) * GBK + l4 * 8];
        #pragma unroll
        for (int ni = 0; ni < 2; ++ni)
            bfr[ni] = *(const bf16x8*)&Bs[(wcol * 32 + ni * 16 + l15) * GBK + l4 * 8];

        #pragma unroll
        for (int mi = 0; mi < 4; ++mi)
            #pragma unroll
            for (int ni = 0; ni < 2; ++ni)
                acc[mi][ni] = __builtin_amdgcn_mfma_f32_16x16x32_bf16(af[mi], bfr[ni], acc[mi][ni], 0, 0, 0);
        __syncthreads();
    }

    #pragma unroll
    for (int mi = 0; mi < 4; ++mi) {
        #pragma unroll
        for (int ni = 0; ni < 2; ++ni) {
            int col = n0 + wcol * 32 + ni * 16 + l15;
            float bb = bias ? bias[col] : 0.0f;
            #pragma unroll
            for (int r = 0; r < 4; ++r) {
                int row = m0 + wrow * 64 + mi * 16 + l4 * 4 + r;
                float vv = acc[mi][ni][r] + bb;
                if (relu) vv = fmaxf(vv, 0.0f);
                C[(size_t)row * N + col] = f2b(vv);
            }
        }
    }
}

// ---------------- swapped-QK^T flash attention, barrier-free k-loop ----------------
// grid (SEQ/64, NH, NB), 256 threads = 4 waves; wave w owns q-rows q0+w*16+l15 (q = l&15)
__global__ __launch_bounds__(256)
void attn_mfma2(const short* __restrict__ qp, const short* __restrict__ kp,
                const short* __restrict__ vt, const int* __restrict__ mask,
                short* __restrict__ attn)
{
    __shared__ float mkf[SEQ];                   // 4KB additive mask cache
    __shared__ __align__(16) char Ps[4 * 2048];  // per-wave P[16q][64k] bf16, XOR-swizzled

    const int tid = threadIdx.x;
    const int l   = tid & 63, w = tid >> 6;
    const int l15 = l & 15,  l4 = l >> 4;
    const int h   = blockIdx.y, b = blockIdx.z;
    const int qrow = blockIdx.x * 64 + w * 16 + l15;
    const size_t baseqk = ((size_t)b * SEQ) * DMODEL + h * HD;
    const size_t basev  = ((size_t)b * DMODEL + h * HD) * SEQ;
    const float sc = 0.044194173824159216f;      // 1/sqrt(512): module scales by dim_out

    for (int i = tid; i < SEQ; i += 256)
        mkf[i] = mask[b * SEQ + i] ? -1.0e30f : 0.0f;
    __syncthreads();   // only block-wide barrier; k-loop is barrier-free

    // Q fragments (B-operand): lane holds Q[q=l15][d = chunk*32 + l4*8 + i]
    bf16x8 qf0, qf1;
    {
        const short* qr = qp + baseqk + (size_t)qrow * DMODEL + l4 * 8;
        qf0 = *(const bf16x8*)qr;
        qf1 = *(const bf16x8*)(qr + 32);
    }

    float m_ = -1.0e30f, l_ = 0.0f;
    f32x4 oacc[4] = {};                          // O^T[d][q]: d = db*16 + l4*4 + r, q = l15
    char* myPs = Ps + w * 2048;
    const int sw = (l15 & 7) << 4;

    for (int k0 = 0; k0 < SEQ; k0 += 64) {
        // ---- S^T[k][q] = K·Q^T : A = K-frag (k=l15 per 16-blk), B = Q-frag ----
        f32x4 s[4];
        #pragma unroll
        for (int c = 0; c < 4; ++c) {
            const short* kr = kp + baseqk + (size_t)(k0 + c * 16 + l15) * DMODEL + l4 * 8;
            bf16x8 kf0 = *(const bf16x8*)kr;
            bf16x8 kf1 = *(const bf16x8*)(kr + 32);
            f32x4 z = {};
            z = __builtin_amdgcn_mfma_f32_16x16x32_bf16(kf0, qf0, z, 0, 0, 0);
            z = __builtin_amdgcn_mfma_f32_16x16x32_bf16(kf1, qf1, z, 0, 0, 0);
            s[c] = z;
        }
        // scale + additive mask; s[c][r] is k = k0 + c*16 + l4*4 + r (same q=l15 for all)
        #pragma unroll
        for (int c = 0; c < 4; ++c) {
            float4 mv = *(const float4*)&mkf[k0 + c * 16 + l4 * 4];
            s[c][0] = s[c][0] * sc + mv.x;
            s[c][1] = s[c][1] * sc + mv.y;
            s[c][2] = s[c][2] * sc + mv.z;
            s[c][3] = s[c][3] * sc + mv.w;
        }
        // ---- online softmax: 16 in-lane values + cross-group (xor 16, 32) ----
        float pm = fmaxf(fmaxf(s[0][0], s[0][1]), fmaxf(s[0][2], s[0][3]));
        pm = fmaxf(pm, fmaxf(fmaxf(s[1][0], s[1][1]), fmaxf(s[1][2], s[1][3])));
        pm = fmaxf(pm, fmaxf(fmaxf(s[2][0], s[2][1]), fmaxf(s[2][2], s[2][3])));
        pm = fmaxf(pm, fmaxf(fmaxf(s[3][0], s[3][1]), fmaxf(s[3][2], s[3][3])));
        pm = fmaxf(pm, __shfl_xor(pm, 16));
        pm = fmaxf(pm, __shfl_xor(pm, 32));
        float mnew  = fmaxf(m_, pm);
        float alpha = __expf(m_ - mnew);
        float rsum  = 0.0f;
        short pb[16];
        #pragma unroll
        for (int c = 0; c < 4; ++c)
            #pragma unroll
            for (int r = 0; r < 4; ++r) {
                float p = __expf(s[c][r] - mnew);
                rsum += p;
                pb[c * 4 + r] = f2b(p);
            }
        rsum += __shfl_xor(rsum, 16);
        rsum += __shfl_xor(rsum, 32);
        l_ = l_ * alpha + rsum;
        m_ = mnew;
        #pragma unroll
        for (int db = 0; db < 4; ++db) {
            oacc[db][0] *= alpha; oacc[db][1] *= alpha;
            oacc[db][2] *= alpha; oacc[db][3] *= alpha;
        }
        // ---- P exchange via wave-private swizzled LDS: write P[q=l15][k] ----
        #pragma unroll
        for (int c = 0; c < 4; ++c) {
            short4 pv; pv.x = pb[c*4+0]; pv.y = pb[c*4+1]; pv.z = pb[c*4+2]; pv.w = pb[c*4+3];
            *(short4*)(myPs + ((l15 * 128 + c * 32 + l4 * 8) ^ sw)) = pv;
        }
        bf16x8 pf0 = *(const bf16x8*)(myPs + ((l15 * 128 +  0 + l4 * 16) ^ sw));
        bf16x8 pf1 = *(const bf16x8*)(myPs + ((l15 * 128 + 64 + l4 * 16) ^ sw));
        // ---- O^T += Vt·P^T : A = Vt-frag (d=l15 per 16-blk), B = P-frag ----
        #pragma unroll
        for (int db = 0; db < 4; ++db) {
            const short* vr = vt + basev + (size_t)(db * 16 + l15) * SEQ + k0 + l4 * 8;
            bf16x8 vf0 = *(const bf16x8*)vr;
            bf16x8 vf1 = *(const bf16x8*)(vr + 32);
            oacc[db] = __builtin_amdgcn_mfma_f32_16x16x32_bf16(vf0, pf0, oacc[db], 0, 0, 0);
            oacc[db] = __builtin_amdgcn_mfma_f32_16x16x32_bf16(vf1, pf1, oacc[db], 0, 0, 0);
        }
    }

    float inv = (m_ > -1.0e29f) ? 1.0f / l_ : 0.0f;   // all-masked row -> 0 (ref: NaN->0)
    #pragma unroll
    for (int db = 0; db < 4; ++db) {
        short4 o;
        o.x = f2b(oacc[db][0] * inv);
        o.y = f2b(oacc[db][1] * inv);
        o.z = f2b(oacc[db][2] * inv);
        o.w = f2b(oacc[db][3] * inv);
        *(short4*)(attn + baseqk + (size_t)qrow * DMODEL + db * 16 + l4 * 4) = o;
    }
}

// ---------------- fused add + LayerNorm (bf16 in, bf16 or fp32 out) ----------------
__global__ __launch_bounds__(256)
void add_ln_b(const short* __restrict__ A, const short* __restrict__ Bv,
              const float* __restrict__ g, const float* __restrict__ beta,
              short* __restrict__ outb, float* __restrict__ outf)
{
    const int row = blockIdx.x;
    const int tid = threadIdx.x;
    const size_t off = (size_t)row * DMODEL;
    short2 a2 = *(const short2*)&A[off + tid * 2];
    short2 c2 = *(const short2*)&Bv[off + tid * 2];
    float x0 = b2f(a2.x) + b2f(c2.x);
    float x1 = b2f(a2.y) + b2f(c2.y);
    float s  = x0 + x1;
    float sq = x0 * x0 + x1 * x1;
    #pragma unroll
    for (int o = 1; o < 64; o <<= 1) {
        s  += __shfl_xor(s,  o);
        sq += __shfl_xor(sq, o);
    }
    __shared__ float ls[4], lq[4];
    const int w = tid >> 6;
    if ((tid & 63) == 0) { ls[w] = s; lq[w] = sq; }
    __syncthreads();
    s  = ls[0] + ls[1] + ls[2] + ls[3];
    sq = lq[0] + lq[1] + lq[2] + lq[3];
    const float mean = s * (1.0f / DMODEL);
    const float var  = sq * (1.0f / DMODEL) - mean * mean;
    const float rs   = rsqrtf(var + 1e-5f);
    const int c0 = tid * 2, c1 = tid * 2 + 1;
    float y0 = (x0 - mean) * rs * g[c0] + beta[c0];
    float y1 = (x1 - mean) * rs * g[c1] + beta[c1];
    if (outb) {
        short2 o; o.x = f2b(y0); o.y = f2b(y1);
        *(short2*)&outb[off + tid * 2] = o;
    } else {
        float2 o; o.x = y0; o.y = y1;
        *(float2*)&outf[off + tid * 2] = o;
    }
}

// ---------------- launch ----------------
extern "C" void kernel_launch(void* const* d_in, const int* in_sizes, int n_in,
                              void* d_out, int out_size, void* d_ws, size_t ws_size,
                              hipStream_t stream)
{
    const float* q    = (const float*)d_in[0];
    const float* k    = (const float*)d_in[1];
    const float* v    = (const float*)d_in[2];
    const int*   mask = (const int*)  d_in[3];
    const float* Wq   = (const float*)d_in[4];
    const float* Wk   = (const float*)d_in[5];
    const float* Wv   = (const float*)d_in[6];
    const float* Wo   = (const float*)d_in[7];
    const float* bo   = (const float*)d_in[8];
    const float* g1   = (const float*)d_in[9];
    const float* b1   = (const float*)d_in[10];
    const float* g2   = (const float*)d_in[11];
    const float* bt2  = (const float*)d_in[12];
    float* out = (float*)d_out;

    short* ws = (short*)d_ws;
    const size_t WSZ  = (size_t)DMODEL * DMODEL;
    const size_t SLOT = (size_t)R_TOT * DMODEL;
    short* wq  = ws;
    short* wk  = ws + WSZ;
    short* wv  = ws + 2 * WSZ;
    short* wo  = ws + 3 * WSZ;
    short* qb  = ws + 4 * WSZ;
    short* kb  = qb + SLOT;
    short* vb  = kb + SLOT;
    short* qpb = vb + SLOT;
    short* kpb = qpb + SLOT;
    short* vtb = kpb + SLOT;     // vt[b][dmodel][SEQ]
    short* at  = qb;             // qb dead after q-projection
    short* y   = kb;             // kb dead after k-projection
    short* z   = vb;             // vb dead after vt GEMM

    const int nCvtBlocks = (3 * N4B + 4 * N4W) / 256;   // 13312
    cvt_all<<<nCvtBlocks, 256, 0, stream>>>(q, k, v, Wq, Wk, Wv, Wo,
                                            qb, kb, vb, wq, wk, wv, wo);

    dim3 gg(DMODEL / GBN, R_TOT / GBM, 1);   // (8, 64)
    gemm_bf16<<<gg, 256, 0, stream>>>(qb, wq, nullptr, qpb, R_TOT, DMODEL, DMODEL, 0, 0, 0, 0);
    gemm_bf16<<<gg, 256, 0, stream>>>(kb, wk, nullptr, kpb, R_TOT, DMODEL, DMODEL, 0, 0, 0, 0);
    // vt[b] = Wv (512x512) @ v_b^T  -> [DMODEL][SEQ], coalesced transposed V-projection
    dim3 gv(SEQ / GBN, DMODEL / GBM, NB);    // (16, 4, 8)
    gemm_bf16<<<gv, 256, 0, stream>>>(wv, vb, nullptr, vtb, DMODEL, SEQ, DMODEL, 0,
                                      0, (long)SEQ * DMODEL, (long)DMODEL * SEQ);

    attn_mfma2<<<dim3(SEQ / 64, NH, NB), 256, 0, stream>>>(qpb, kpb, vtb, mask, at);

    add_ln_b<<<R_TOT, 256, 0, stream>>>(qpb, at, g1, b1, y, nullptr);

    gemm_bf16<<<gg, 256, 0, stream>>>(y, wo, bo, z, R_TOT, DMODEL, DMODEL, 1, 0, 0, 0);

    add_ln_b<<<R_TOT, 256, 0, stream>>>(y, z, g2, bt2, nullptr, out);
}

// Round 4
// 150.448 us; speedup vs baseline: 3.8085x; 1.4174x over previous
//
#include <hip/hip_runtime.h>
#include <math.h>
#include <stdint.h>

#define NB 8
#define SEQ 1024
#define DMODEL 512
#define NH 8
#define HD 64
#define R_TOT (NB * SEQ)   // 8192 rows

typedef __attribute__((ext_vector_type(8))) short bf16x8;
typedef __attribute__((ext_vector_type(4))) float f32x4;

__device__ __forceinline__ short f2b(float x) {
    uint32_t u = __float_as_uint(x);
    u += 0x7FFF + ((u >> 16) & 1);          // round-to-nearest-even
    return (short)(u >> 16);
}
__device__ __forceinline__ float b2f(short s) {
    return __uint_as_float(((uint32_t)(uint16_t)s) << 16);
}

#define GLD_LDS16(g, l)                                                        \
    __builtin_amdgcn_global_load_lds(                                          \
        (const __attribute__((address_space(1))) uint32_t*)(g),                \
        (__attribute__((address_space(3))) uint32_t*)(l), 16, 0, 0)

// ---------------- merged fp32 -> bf16 convert (q,k,v + 4 weights in 1 launch) ----------------
#define N4B (R_TOT * DMODEL / 4)    // 1048576 float4 per activation tensor
#define N4W (DMODEL * DMODEL / 4)   // 65536 per weight

__global__ __launch_bounds__(256)
void cvt_all(const float* __restrict__ q, const float* __restrict__ k, const float* __restrict__ v,
             const float* __restrict__ wq, const float* __restrict__ wk,
             const float* __restrict__ wv, const float* __restrict__ wo,
             short* dq, short* dk, short* dv, short* dwq, short* dwk, short* dwv, short* dwo)
{
    long i = (long)blockIdx.x * 256 + threadIdx.x;
    const float* s; short* d; long off;
    if (i < (long)N4B)          { s = q;  d = dq;  off = i; }
    else if (i < 2L * N4B)      { s = k;  d = dk;  off = i - N4B; }
    else if (i < 3L * N4B)      { s = v;  d = dv;  off = i - 2L * N4B; }
    else {
        long j = i - 3L * N4B;
        int  w = (int)(j >> 16);           // j / N4W
        off = j & (N4W - 1);
        s = (w == 0) ? wq : (w == 1) ? wk : (w == 2) ? wv : wo;
        d = (w == 0) ? dwq : (w == 1) ? dwk : (w == 2) ? dwv : dwo;
    }
    float4 x = ((const float4*)s)[off];
    short4 o;
    o.x = f2b(x.x); o.y = f2b(x.y); o.z = f2b(x.z); o.w = f2b(x.w);
    ((short4*)d)[off] = o;
}

// ---------------- bf16 MFMA GEMM:  C[M,N] = act(A[M,K] @ B[N,K]^T + bias), batched ----------------
#define GBM 128
#define GBN 64
#define GBK 32

__global__ __launch_bounds__(256)
void gemm_bf16(const short* __restrict__ A, const short* __restrict__ Bm,
               const float* __restrict__ bias, short* __restrict__ C,
               int M, int N, int K, int relu,
               long sAb, long sBb, long sCb)
{
    __shared__ short As[GBM * GBK];
    __shared__ short Bs[GBN * GBK];
    const int tid = threadIdx.x;
    const int l   = tid & 63, w = tid >> 6;
    const int l15 = l & 15,  l4 = l >> 4;
    const int wrow = w >> 1, wcol = w & 1;
    const int m0 = blockIdx.y * GBM, n0 = blockIdx.x * GBN;
    A  += (long)blockIdx.z * sAb;
    Bm += (long)blockIdx.z * sBb;
    C  += (long)blockIdx.z * sCb;

    f32x4 acc[4][2] = {};

    for (int k0 = 0; k0 < K; k0 += GBK) {
        {
            int ch = tid;
            GLD_LDS16(A + (size_t)(m0 + (ch >> 2)) * K + k0 + (ch & 3) * 8, &As[ch * 8]);
            ch = tid + 256;
            GLD_LDS16(A + (size_t)(m0 + (ch >> 2)) * K + k0 + (ch & 3) * 8, &As[ch * 8]);
            ch = tid;
            GLD_LDS16(Bm + (size_t)(n0 + (ch >> 2)) * K + k0 + (ch & 3) * 8, &Bs[ch * 8]);
        }
        __syncthreads();

        bf16x8 af[4], bfr[2];
        #pragma unroll
        for (int mi = 0; mi < 4; ++mi)
            af[mi] = *(const bf16x8*)&As[(wrow * 64 + mi * 16 + l15) * GBK + l4 * 8];
        #pragma unroll
        for (int ni = 0; ni < 2; ++ni)
            bfr[ni] = *(const bf16x8*)&Bs[(wcol * 32 + ni * 16 + l15) * GBK + l4 * 8];

        #pragma unroll
        for (int mi = 0; mi < 4; ++mi)
            #pragma unroll
            for (int ni = 0; ni < 2; ++ni)
                acc[mi][ni] = __builtin_amdgcn_mfma_f32_16x16x32_bf16(af[mi], bfr[ni], acc[mi][ni], 0, 0, 0);
        __syncthreads();
    }

    #pragma unroll
    for (int mi = 0; mi < 4; ++mi) {
        #pragma unroll
        for (int ni = 0; ni < 2; ++ni) {
            int col = n0 + wcol * 32 + ni * 16 + l15;
            float bb = bias ? bias[col] : 0.0f;
            #pragma unroll
            for (int r = 0; r < 4; ++r) {
                int row = m0 + wrow * 64 + mi * 16 + l4 * 4 + r;
                float vv = acc[mi][ni][r] + bb;
                if (relu) vv = fmaxf(vv, 0.0f);
                C[(size_t)row * N + col] = f2b(vv);
            }
        }
    }
}

// ---------------- swapped-QK^T flash attention with double-buffered LDS K/Vt ----------------
// grid (SEQ/64, NH, NB), 256 threads = 4 waves; wave w owns q-rows blk*64 + w*16 + (l&15)
__global__ __launch_bounds__(256)
void attn_mfma3(const short* __restrict__ qp, const short* __restrict__ kp,
                const short* __restrict__ vt, const int* __restrict__ mask,
                short* __restrict__ attn)
{
    __shared__ short Kb[2][64 * 64];             // K tile  [k-row][d], swizzled rows
    __shared__ short Vb[2][64 * 64];             // Vt tile [d-row][k], swizzled rows
    __shared__ float mkf[SEQ];                   // 4KB additive mask cache
    __shared__ __align__(16) char Ps[4 * 2048];  // per-wave P[16q][64k] bf16, XOR-swizzled

    const int tid = threadIdx.x;
    const int l   = tid & 63, w = tid >> 6;
    const int l15 = l & 15,  l4 = l >> 4;
    const int h   = blockIdx.y, b = blockIdx.z;
    const int qrow = blockIdx.x * 64 + w * 16 + l15;
    const size_t baseqk = ((size_t)b * SEQ) * DMODEL + h * HD;
    const size_t basev  = ((size_t)b * DMODEL + h * HD) * SEQ;
    const float sc = 0.044194173824159216f;      // 1/sqrt(512): module scales by dim_out

    // staging geometry: chunk ch (0..511) -> LDS linear ch*16B; row=ch>>3; source col
    // pre-swizzled so that (read addr ^ (row&7)<<4) sees logical layout (rule #21)
    const int ch0 = tid, ch1 = tid + 256;
    const int r0 = ch0 >> 3, r1 = ch1 >> 3;
    const int so0 = (((ch0 & 7) * 16) ^ ((r0 & 7) << 4)) >> 1;   // element offset
    const int so1 = (((ch1 & 7) * 16) ^ ((r1 & 7) << 4)) >> 1;
    const short* kph = kp + baseqk;
    const short* vth = vt + basev;

#define STAGE(t, bufi) do {                                                          \
        GLD_LDS16(kph + (size_t)((t) * 64 + r0) * DMODEL + so0, &Kb[bufi][ch0 * 8]); \
        GLD_LDS16(kph + (size_t)((t) * 64 + r1) * DMODEL + so1, &Kb[bufi][ch1 * 8]); \
        GLD_LDS16(vth + (size_t)r0 * SEQ + (t) * 64 + so0,      &Vb[bufi][ch0 * 8]); \
        GLD_LDS16(vth + (size_t)r1 * SEQ + (t) * 64 + so1,      &Vb[bufi][ch1 * 8]); \
    } while (0)

    for (int i = tid; i < SEQ; i += 256)
        mkf[i] = mask[b * SEQ + i] ? -1.0e30f : 0.0f;

    // Q fragments (B-operand): lane holds Q[q=l15][d = chunk*32 + l4*8 + i]
    bf16x8 qf0, qf1;
    {
        const short* qr = qp + baseqk + (size_t)qrow * DMODEL + l4 * 8;
        qf0 = *(const bf16x8*)qr;
        qf1 = *(const bf16x8*)(qr + 32);
    }

    STAGE(0, 0);
    __syncthreads();   // drains vmcnt(0): tile 0 resident

    float m_ = -1.0e30f, l_ = 0.0f;
    f32x4 oacc[4] = {};                          // O^T[d][q]: d = db*16 + l4*4 + r, q = l15
    char* myPs = Ps + w * 2048;
    const int swp = (l15 & 7) << 4;

    for (int t = 0; t < 16; ++t) {
        const int cur = t & 1;
        if (t < 15) STAGE(t + 1, cur ^ 1);       // prefetch overlaps compute below

        // ---- S^T[k][q] = K·Q^T from LDS (swizzled b128 reads) ----
        f32x4 s[4];
        #pragma unroll
        for (int c = 0; c < 4; ++c) {
            int r = c * 16 + l15;
            const short* kb = &Kb[cur][r * 64];
            int o0 = ((l4 * 16) ^ ((r & 7) << 4)) >> 1;
            int o1 = ((64 + l4 * 16) ^ ((r & 7) << 4)) >> 1;
            bf16x8 kf0 = *(const bf16x8*)(kb + o0);
            bf16x8 kf1 = *(const bf16x8*)(kb + o1);
            f32x4 z = {};
            z = __builtin_amdgcn_mfma_f32_16x16x32_bf16(kf0, qf0, z, 0, 0, 0);
            z = __builtin_amdgcn_mfma_f32_16x16x32_bf16(kf1, qf1, z, 0, 0, 0);
            s[c] = z;
        }
        // scale + additive mask; s[c][r] is k = t*64 + c*16 + l4*4 + r (q = l15)
        #pragma unroll
        for (int c = 0; c < 4; ++c) {
            float4 mv = *(const float4*)&mkf[t * 64 + c * 16 + l4 * 4];
            s[c][0] = s[c][0] * sc + mv.x;
            s[c][1] = s[c][1] * sc + mv.y;
            s[c][2] = s[c][2] * sc + mv.z;
            s[c][3] = s[c][3] * sc + mv.w;
        }
        // ---- online softmax: 16 in-lane values + cross-group (xor 16, 32) ----
        float pm = fmaxf(fmaxf(s[0][0], s[0][1]), fmaxf(s[0][2], s[0][3]));
        pm = fmaxf(pm, fmaxf(fmaxf(s[1][0], s[1][1]), fmaxf(s[1][2], s[1][3])));
        pm = fmaxf(pm, fmaxf(fmaxf(s[2][0], s[2][1]), fmaxf(s[2][2], s[2][3])));
        pm = fmaxf(pm, fmaxf(fmaxf(s[3][0], s[3][1]), fmaxf(s[3][2], s[3][3])));
        pm = fmaxf(pm, __shfl_xor(pm, 16));
        pm = fmaxf(pm, __shfl_xor(pm, 32));
        float mnew  = fmaxf(m_, pm);
        float alpha = __expf(m_ - mnew);
        float rsum  = 0.0f;
        short pb[16];
        #pragma unroll
        for (int c = 0; c < 4; ++c)
            #pragma unroll
            for (int r = 0; r < 4; ++r) {
                float p = __expf(s[c][r] - mnew);
                rsum += p;
                pb[c * 4 + r] = f2b(p);
            }
        rsum += __shfl_xor(rsum, 16);
        rsum += __shfl_xor(rsum, 32);
        l_ = l_ * alpha + rsum;
        m_ = mnew;
        #pragma unroll
        for (int db = 0; db < 4; ++db) {
            oacc[db][0] *= alpha; oacc[db][1] *= alpha;
            oacc[db][2] *= alpha; oacc[db][3] *= alpha;
        }
        // ---- P exchange via wave-private swizzled LDS ----
        #pragma unroll
        for (int c = 0; c < 4; ++c) {
            short4 pv; pv.x = pb[c*4+0]; pv.y = pb[c*4+1]; pv.z = pb[c*4+2]; pv.w = pb[c*4+3];
            *(short4*)(myPs + ((l15 * 128 + c * 32 + l4 * 8) ^ swp)) = pv;
        }
        bf16x8 pf0 = *(const bf16x8*)(myPs + ((l15 * 128 +  0 + l4 * 16) ^ swp));
        bf16x8 pf1 = *(const bf16x8*)(myPs + ((l15 * 128 + 64 + l4 * 16) ^ swp));
        // ---- O^T += Vt·P^T from LDS ----
        #pragma unroll
        for (int db = 0; db < 4; ++db) {
            int d = db * 16 + l15;
            const short* vb = &Vb[cur][d * 64];
            int o0 = ((l4 * 16) ^ ((d & 7) << 4)) >> 1;
            int o1 = ((64 + l4 * 16) ^ ((d & 7) << 4)) >> 1;
            bf16x8 vf0 = *(const bf16x8*)(vb + o0);
            bf16x8 vf1 = *(const bf16x8*)(vb + o1);
            oacc[db] = __builtin_amdgcn_mfma_f32_16x16x32_bf16(vf0, pf0, oacc[db], 0, 0, 0);
            oacc[db] = __builtin_amdgcn_mfma_f32_16x16x32_bf16(vf1, pf1, oacc[db], 0, 0, 0);
        }
        __syncthreads();   // drains vmcnt (tile t+1 landed) + closes buf[cur] reads
    }
#undef STAGE

    float inv = (m_ > -1.0e29f) ? 1.0f / l_ : 0.0f;   // all-masked row -> 0 (ref: NaN->0)
    #pragma unroll
    for (int db = 0; db < 4; ++db) {
        short4 o;
        o.x = f2b(oacc[db][0] * inv);
        o.y = f2b(oacc[db][1] * inv);
        o.z = f2b(oacc[db][2] * inv);
        o.w = f2b(oacc[db][3] * inv);
        *(short4*)(attn + baseqk + (size_t)qrow * DMODEL + db * 16 + l4 * 4) = o;
    }
}

// ---------------- fused add + LayerNorm (bf16 in, bf16 or fp32 out) ----------------
__global__ __launch_bounds__(256)
void add_ln_b(const short* __restrict__ A, const short* __restrict__ Bv,
              const float* __restrict__ g, const float* __restrict__ beta,
              short* __restrict__ outb, float* __restrict__ outf)
{
    const int row = blockIdx.x;
    const int tid = threadIdx.x;
    const size_t off = (size_t)row * DMODEL;
    short2 a2 = *(const short2*)&A[off + tid * 2];
    short2 c2 = *(const short2*)&Bv[off + tid * 2];
    float x0 = b2f(a2.x) + b2f(c2.x);
    float x1 = b2f(a2.y) + b2f(c2.y);
    float s  = x0 + x1;
    float sq = x0 * x0 + x1 * x1;
    #pragma unroll
    for (int o = 1; o < 64; o <<= 1) {
        s  += __shfl_xor(s,  o);
        sq += __shfl_xor(sq, o);
    }
    __shared__ float ls[4], lq[4];
    const int w = tid >> 6;
    if ((tid & 63) == 0) { ls[w] = s; lq[w] = sq; }
    __syncthreads();
    s  = ls[0] + ls[1] + ls[2] + ls[3];
    sq = lq[0] + lq[1] + lq[2] + lq[3];
    const float mean = s * (1.0f / DMODEL);
    const float var  = sq * (1.0f / DMODEL) - mean * mean;
    const float rs   = rsqrtf(var + 1e-5f);
    const int c0 = tid * 2, c1 = tid * 2 + 1;
    float y0 = (x0 - mean) * rs * g[c0] + beta[c0];
    float y1 = (x1 - mean) * rs * g[c1] + beta[c1];
    if (outb) {
        short2 o; o.x = f2b(y0); o.y = f2b(y1);
        *(short2*)&outb[off + tid * 2] = o;
    } else {
        float2 o; o.x = y0; o.y = y1;
        *(float2*)&outf[off + tid * 2] = o;
    }
}

// ---------------- launch ----------------
extern "C" void kernel_launch(void* const* d_in, const int* in_sizes, int n_in,
                              void* d_out, int out_size, void* d_ws, size_t ws_size,
                              hipStream_t stream)
{
    const float* q    = (const float*)d_in[0];
    const float* k    = (const float*)d_in[1];
    const float* v    = (const float*)d_in[2];
    const int*   mask = (const int*)  d_in[3];
    const float* Wq   = (const float*)d_in[4];
    const float* Wk   = (const float*)d_in[5];
    const float* Wv   = (const float*)d_in[6];
    const float* Wo   = (const float*)d_in[7];
    const float* bo   = (const float*)d_in[8];
    const float* g1   = (const float*)d_in[9];
    const float* b1   = (const float*)d_in[10];
    const float* g2   = (const float*)d_in[11];
    const float* bt2  = (const float*)d_in[12];
    float* out = (float*)d_out;

    short* ws = (short*)d_ws;
    const size_t WSZ  = (size_t)DMODEL * DMODEL;
    const size_t SLOT = (size_t)R_TOT * DMODEL;
    short* wq  = ws;
    short* wk  = ws + WSZ;
    short* wv  = ws + 2 * WSZ;
    short* wo  = ws + 3 * WSZ;
    short* qb  = ws + 4 * WSZ;
    short* kb  = qb + SLOT;
    short* vb  = kb + SLOT;
    short* qpb = vb + SLOT;
    short* kpb = qpb + SLOT;
    short* vtb = kpb + SLOT;     // vt[b][dmodel][SEQ]
    short* at  = qb;             // qb dead after q-projection
    short* y   = kb;             // kb dead after k-projection
    short* z   = vb;             // vb dead after vt GEMM

    const int nCvtBlocks = (3 * N4B + 4 * N4W) / 256;   // 13312
    cvt_all<<<nCvtBlocks, 256, 0, stream>>>(q, k, v, Wq, Wk, Wv, Wo,
                                            qb, kb, vb, wq, wk, wv, wo);

    dim3 gg(DMODEL / GBN, R_TOT / GBM, 1);   // (8, 64)
    gemm_bf16<<<gg, 256, 0, stream>>>(qb, wq, nullptr, qpb, R_TOT, DMODEL, DMODEL, 0, 0, 0, 0);
    gemm_bf16<<<gg, 256, 0, stream>>>(kb, wk, nullptr, kpb, R_TOT, DMODEL, DMODEL, 0, 0, 0, 0);
    // vt[b] = Wv (512x512) @ v_b^T  -> [DMODEL][SEQ], coalesced transposed V-projection
    dim3 gv(SEQ / GBN, DMODEL / GBM, NB);    // (16, 4, 8)
    gemm_bf16<<<gv, 256, 0, stream>>>(wv, vb, nullptr, vtb, DMODEL, SEQ, DMODEL, 0,
                                      0, (long)SEQ * DMODEL, (long)DMODEL * SEQ);

    attn_mfma3<<<dim3(SEQ / 64, NH, NB), 256, 0, stream>>>(qpb, kpb, vtb, mask, at);

    add_ln_b<<<R_TOT, 256, 0, stream>>>(qpb, at, g1, b1, y, nullptr);

    gemm_bf16<<<gg, 256, 0, stream>>>(y, wo, bo, z, R_TOT, DMODEL, DMODEL, 1, 0, 0, 0);

    add_ln_b<<<R_TOT, 256, 0, stream>>>(y, z, g2, bt2, nullptr, out);
}

// Round 5
// 141.190 us; speedup vs baseline: 4.0582x; 1.0656x over previous
//
#include <hip/hip_runtime.h>
#include <math.h>
#include <stdint.h>

#define NB 8
#define SEQ 1024
#define DMODEL 512
#define NH 8
#define HD 64
#define R_TOT (NB * SEQ)   // 8192 rows

typedef __attribute__((ext_vector_type(8))) short bf16x8;
typedef __attribute__((ext_vector_type(4))) float f32x4;

__device__ __forceinline__ short f2b(float x) {
    uint32_t u = __float_as_uint(x);
    u += 0x7FFF + ((u >> 16) & 1);          // round-to-nearest-even
    return (short)(u >> 16);
}
__device__ __forceinline__ float b2f(short s) {
    return __uint_as_float(((uint32_t)(uint16_t)s) << 16);
}
__device__ __forceinline__ uint32_t cvtpk_bf16(float lo, float hi) {
    uint32_t r;
    asm("v_cvt_pk_bf16_f32 %0, %1, %2" : "=v"(r) : "v"(lo), "v"(hi));
    return r;
}

#define GLD_LDS16(g, l)                                                        \
    __builtin_amdgcn_global_load_lds(                                          \
        (const __attribute__((address_space(1))) uint32_t*)(g),                \
        (__attribute__((address_space(3))) uint32_t*)(l), 16, 0, 0)

// ---------------- merged fp32 -> bf16 convert (q,k,v + 4 weights in 1 launch) ----------------
#define N4B (R_TOT * DMODEL / 4)    // 1048576 float4 per activation tensor
#define N4W (DMODEL * DMODEL / 4)   // 65536 per weight

__global__ __launch_bounds__(256)
void cvt_all(const float* __restrict__ q, const float* __restrict__ k, const float* __restrict__ v,
             const float* __restrict__ wq, const float* __restrict__ wk,
             const float* __restrict__ wv, const float* __restrict__ wo,
             short* dq, short* dk, short* dv, short* dwq, short* dwk, short* dwv, short* dwo)
{
    long i = (long)blockIdx.x * 256 + threadIdx.x;
    const float* s; short* d; long off;
    if (i < (long)N4B)          { s = q;  d = dq;  off = i; }
    else if (i < 2L * N4B)      { s = k;  d = dk;  off = i - N4B; }
    else if (i < 3L * N4B)      { s = v;  d = dv;  off = i - 2L * N4B; }
    else {
        long j = i - 3L * N4B;
        int  w = (int)(j >> 16);           // j / N4W
        off = j & (N4W - 1);
        s = (w == 0) ? wq : (w == 1) ? wk : (w == 2) ? wv : wo;
        d = (w == 0) ? dwq : (w == 1) ? dwk : (w == 2) ? dwv : dwo;
    }
    float4 x = ((const float4*)s)[off];
    short4 o;
    o.x = f2b(x.x); o.y = f2b(x.y); o.z = f2b(x.z); o.w = f2b(x.w);
    ((short4*)d)[off] = o;
}

// ---------------- bf16 MFMA GEMM:  C[M,N] = act((A[M,K] @ B[N,K]^T + bias)*oscale), batched ----------------
#define GBM 128
#define GBN 64
#define GBK 32

__global__ __launch_bounds__(256)
void gemm_bf16(const short* __restrict__ A, const short* __restrict__ Bm,
               const float* __restrict__ bias, short* __restrict__ C,
               int M, int N, int K, int relu, float oscale,
               long sAb, long sBb, long sCb)
{
    __shared__ short As[GBM * GBK];
    __shared__ short Bs[GBN * GBK];
    const int tid = threadIdx.x;
    const int l   = tid & 63, w = tid >> 6;
    const int l15 = l & 15,  l4 = l >> 4;
    const int wrow = w >> 1, wcol = w & 1;
    const int m0 = blockIdx.y * GBM, n0 = blockIdx.x * GBN;
    A  += (long)blockIdx.z * sAb;
    Bm += (long)blockIdx.z * sBb;
    C  += (long)blockIdx.z * sCb;

    f32x4 acc[4][2] = {};

    for (int k0 = 0; k0 < K; k0 += GBK) {
        {
            int ch = tid;
            GLD_LDS16(A + (size_t)(m0 + (ch >> 2)) * K + k0 + (ch & 3) * 8, &As[ch * 8]);
            ch = tid + 256;
            GLD_LDS16(A + (size_t)(m0 + (ch >> 2)) * K + k0 + (ch & 3) * 8, &As[ch * 8]);
            ch = tid;
            GLD_LDS16(Bm + (size_t)(n0 + (ch >> 2)) * K + k0 + (ch & 3) * 8, &Bs[ch * 8]);
        }
        __syncthreads();

        bf16x8 af[4], bfr[2];
        #pragma unroll
        for (int mi = 0; mi < 4; ++mi)
            af[mi] = *(const bf16x8*)&As[(wrow * 64 + mi * 16 + l15) * GBK + l4 * 8];
        #pragma unroll
        for (int ni = 0; ni < 2; ++ni)
            bfr[ni] = *(const bf16x8*)&Bs[(wcol * 32 + ni * 16 + l15) * GBK + l4 * 8];

        #pragma unroll
        for (int mi = 0; mi < 4; ++mi)
            #pragma unroll
            for (int ni = 0; ni < 2; ++ni)
                acc[mi][ni] = __builtin_amdgcn_mfma_f32_16x16x32_bf16(af[mi], bfr[ni], acc[mi][ni], 0, 0, 0);
        __syncthreads();
    }

    #pragma unroll
    for (int mi = 0; mi < 4; ++mi) {
        #pragma unroll
        for (int ni = 0; ni < 2; ++ni) {
            int col = n0 + wcol * 32 + ni * 16 + l15;
            float bb = bias ? bias[col] : 0.0f;
            #pragma unroll
            for (int r = 0; r < 4; ++r) {
                int row = m0 + wrow * 64 + mi * 16 + l4 * 4 + r;
                float vv = (acc[mi][ni][r] + bb) * oscale;
                if (relu) vv = fmaxf(vv, 0.0f);
                C[(size_t)row * N + col] = f2b(vv);
            }
        }
    }
}

// ---------------- swapped-QK^T flash attention, log2-domain softmax, dbuf LDS ----------------
// grid (SEQ/64, NH, NB), 256 threads = 4 waves; wave w owns q-rows blk*64 + w*16 + (l&15)
// kp comes PRE-SCALED by (1/sqrt(512))*log2(e) from its projection GEMM.
__global__ __launch_bounds__(256, 4)
void attn_mfma4(const short* __restrict__ qp, const short* __restrict__ kp,
                const short* __restrict__ vt, const int* __restrict__ mask,
                short* __restrict__ attn)
{
    __shared__ short Kb[2][64 * 64];             // K tile  [k-row][d], swizzled rows
    __shared__ short Vb[2][64 * 64];             // Vt tile [d-row][k], swizzled rows
    __shared__ __align__(16) char Ps[4 * 2048];  // per-wave P[16q][64k] bf16, XOR-swizzled
    // total LDS = 40960 B -> exactly 4 blocks/CU

    const int tid = threadIdx.x;
    const int l   = tid & 63, w = tid >> 6;
    const int l15 = l & 15,  l4 = l >> 4;
    const int h   = blockIdx.y, b = blockIdx.z;
    const int qrow = blockIdx.x * 64 + w * 16 + l15;
    const size_t baseqk = ((size_t)b * SEQ) * DMODEL + h * HD;
    const size_t basev  = ((size_t)b * DMODEL + h * HD) * SEQ;

    const int ch0 = tid, ch1 = tid + 256;
    const int r0 = ch0 >> 3, r1 = ch1 >> 3;
    const int so0 = (((ch0 & 7) * 16) ^ ((r0 & 7) << 4)) >> 1;   // pre-swizzled src (rule #21)
    const int so1 = (((ch1 & 7) * 16) ^ ((r1 & 7) << 4)) >> 1;
    const short* kph = kp + baseqk;
    const short* vth = vt + basev;
    const int*   mrow = mask + b * SEQ;

#define STAGE(t, bufi) do {                                                          \
        GLD_LDS16(kph + (size_t)((t) * 64 + r0) * DMODEL + so0, &Kb[bufi][ch0 * 8]); \
        GLD_LDS16(kph + (size_t)((t) * 64 + r1) * DMODEL + so1, &Kb[bufi][ch1 * 8]); \
        GLD_LDS16(vth + (size_t)r0 * SEQ + (t) * 64 + so0,      &Vb[bufi][ch0 * 8]); \
        GLD_LDS16(vth + (size_t)r1 * SEQ + (t) * 64 + so1,      &Vb[bufi][ch1 * 8]); \
    } while (0)

    // Q fragments (B-operand): lane holds Q[q=l15][d = chunk*32 + l4*8 + i]
    bf16x8 qf0, qf1;
    {
        const short* qr = qp + baseqk + (size_t)qrow * DMODEL + l4 * 8;
        qf0 = *(const bf16x8*)qr;
        qf1 = *(const bf16x8*)(qr + 32);
    }

    STAGE(0, 0);
    __syncthreads();   // vmcnt(0) drain: tile 0 resident

    float m_ = -1.0e30f, l_ = 0.0f;
    f32x4 oacc[4] = {};                          // O^T[d][q]: d = db*16 + l4*4 + r, q = l15
    char* myPs = Ps + w * 2048;
    const int swp = (l15 & 7) << 4;

    for (int t = 0; t < 16; ++t) {
        const int cur = t & 1;
        if (t < 15) STAGE(t + 1, cur ^ 1);       // prefetch overlaps compute

        // ---- S^T[k][q] = K·Q^T from LDS (s is already logits*log2e) ----
        f32x4 s[4];
        __builtin_amdgcn_s_setprio(1);
        #pragma unroll
        for (int c = 0; c < 4; ++c) {
            int r = c * 16 + l15;
            const short* kb = &Kb[cur][r * 64];
            int o0 = ((l4 * 16) ^ ((r & 7) << 4)) >> 1;
            int o1 = ((64 + l4 * 16) ^ ((r & 7) << 4)) >> 1;
            bf16x8 kf0 = *(const bf16x8*)(kb + o0);
            bf16x8 kf1 = *(const bf16x8*)(kb + o1);
            f32x4 z = {};
            z = __builtin_amdgcn_mfma_f32_16x16x32_bf16(kf0, qf0, z, 0, 0, 0);
            z = __builtin_amdgcn_mfma_f32_16x16x32_bf16(kf1, qf1, z, 0, 0, 0);
            s[c] = z;
        }
        __builtin_amdgcn_s_setprio(0);

        // ---- mask: s -> -1e30 where masked (k = t*64 + c*16 + l4*4 + r) ----
        #pragma unroll
        for (int c = 0; c < 4; ++c) {
            int4 mi = *(const int4*)&mrow[t * 64 + c * 16 + l4 * 4];
            s[c][0] = mi.x ? -1.0e30f : s[c][0];
            s[c][1] = mi.y ? -1.0e30f : s[c][1];
            s[c][2] = mi.z ? -1.0e30f : s[c][2];
            s[c][3] = mi.w ? -1.0e30f : s[c][3];
        }

        // ---- online softmax in exp2 domain ----
        float x0 = fmaxf(fmaxf(s[0][0], s[0][1]), fmaxf(s[0][2], s[0][3]));
        float x1 = fmaxf(fmaxf(s[1][0], s[1][1]), fmaxf(s[1][2], s[1][3]));
        float x2 = fmaxf(fmaxf(s[2][0], s[2][1]), fmaxf(s[2][2], s[2][3]));
        float x3 = fmaxf(fmaxf(s[3][0], s[3][1]), fmaxf(s[3][2], s[3][3]));
        float pm = fmaxf(fmaxf(x0, x1), fmaxf(x2, x3));
        pm = fmaxf(pm, __shfl_xor(pm, 16));
        pm = fmaxf(pm, __shfl_xor(pm, 32));
        if (pm > m_ + 8.0f) {                    // defer-max (T13): rescale only on growth
            float al = exp2f(m_ - pm);
            l_ *= al;
            #pragma unroll
            for (int db = 0; db < 4; ++db) {
                oacc[db][0] *= al; oacc[db][1] *= al;
                oacc[db][2] *= al; oacc[db][3] *= al;
            }
            m_ = pm;
        }
        float p[16];
        #pragma unroll
        for (int c = 0; c < 4; ++c)
            #pragma unroll
            for (int r = 0; r < 4; ++r)
                p[c * 4 + r] = exp2f(s[c][r] - m_);
        float rsum = ((p[0] + p[1]) + (p[2] + p[3])) + ((p[4] + p[5]) + (p[6] + p[7]))
                   + ((p[8] + p[9]) + (p[10] + p[11])) + ((p[12] + p[13]) + (p[14] + p[15]));
        rsum += __shfl_xor(rsum, 16);
        rsum += __shfl_xor(rsum, 32);
        l_ += rsum;

        // ---- P pack (cvt_pk) + exchange via wave-private swizzled LDS ----
        #pragma unroll
        for (int c = 0; c < 4; ++c) {
            uint2 u;
            u.x = cvtpk_bf16(p[c * 4 + 0], p[c * 4 + 1]);
            u.y = cvtpk_bf16(p[c * 4 + 2], p[c * 4 + 3]);
            *(uint2*)(myPs + ((l15 * 128 + c * 32 + l4 * 8) ^ swp)) = u;
        }
        bf16x8 pf0 = *(const bf16x8*)(myPs + ((l15 * 128 +  0 + l4 * 16) ^ swp));
        bf16x8 pf1 = *(const bf16x8*)(myPs + ((l15 * 128 + 64 + l4 * 16) ^ swp));

        // ---- O^T += Vt·P^T from LDS ----
        __builtin_amdgcn_s_setprio(1);
        #pragma unroll
        for (int db = 0; db < 4; ++db) {
            int d = db * 16 + l15;
            const short* vb = &Vb[cur][d * 64];
            int o0 = ((l4 * 16) ^ ((d & 7) << 4)) >> 1;
            int o1 = ((64 + l4 * 16) ^ ((d & 7) << 4)) >> 1;
            bf16x8 vf0 = *(const bf16x8*)(vb + o0);
            bf16x8 vf1 = *(const bf16x8*)(vb + o1);
            oacc[db] = __builtin_amdgcn_mfma_f32_16x16x32_bf16(vf0, pf0, oacc[db], 0, 0, 0);
            oacc[db] = __builtin_amdgcn_mfma_f32_16x16x32_bf16(vf1, pf1, oacc[db], 0, 0, 0);
        }
        __builtin_amdgcn_s_setprio(0);
        __syncthreads();   // tile t+1 landed (vmcnt drain) + closes buf[cur] reads
    }
#undef STAGE

    float inv = (m_ > -1.0e29f) ? 1.0f / l_ : 0.0f;   // all-masked row -> 0 (ref: NaN->0)
    #pragma unroll
    for (int db = 0; db < 4; ++db) {
        short4 o;
        o.x = f2b(oacc[db][0] * inv);
        o.y = f2b(oacc[db][1] * inv);
        o.z = f2b(oacc[db][2] * inv);
        o.w = f2b(oacc[db][3] * inv);
        *(short4*)(attn + baseqk + (size_t)qrow * DMODEL + db * 16 + l4 * 4) = o;
    }
}

// ---------------- fused add + LayerNorm (bf16 in, bf16 or fp32 out) ----------------
__global__ __launch_bounds__(256)
void add_ln_b(const short* __restrict__ A, const short* __restrict__ Bv,
              const float* __restrict__ g, const float* __restrict__ beta,
              short* __restrict__ outb, float* __restrict__ outf)
{
    const int row = blockIdx.x;
    const int tid = threadIdx.x;
    const size_t off = (size_t)row * DMODEL;
    short2 a2 = *(const short2*)&A[off + tid * 2];
    short2 c2 = *(const short2*)&Bv[off + tid * 2];
    float x0 = b2f(a2.x) + b2f(c2.x);
    float x1 = b2f(a2.y) + b2f(c2.y);
    float s  = x0 + x1;
    float sq = x0 * x0 + x1 * x1;
    #pragma unroll
    for (int o = 1; o < 64; o <<= 1) {
        s  += __shfl_xor(s,  o);
        sq += __shfl_xor(sq, o);
    }
    __shared__ float ls[4], lq[4];
    const int w = tid >> 6;
    if ((tid & 63) == 0) { ls[w] = s; lq[w] = sq; }
    __syncthreads();
    s  = ls[0] + ls[1] + ls[2] + ls[3];
    sq = lq[0] + lq[1] + lq[2] + lq[3];
    const float mean = s * (1.0f / DMODEL);
    const float var  = sq * (1.0f / DMODEL) - mean * mean;
    const float rs   = rsqrtf(var + 1e-5f);
    const int c0 = tid * 2, c1 = tid * 2 + 1;
    float y0 = (x0 - mean) * rs * g[c0] + beta[c0];
    float y1 = (x1 - mean) * rs * g[c1] + beta[c1];
    if (outb) {
        short2 o; o.x = f2b(y0); o.y = f2b(y1);
        *(short2*)&outb[off + tid * 2] = o;
    } else {
        float2 o; o.x = y0; o.y = y1;
        *(float2*)&outf[off + tid * 2] = o;
    }
}

// ---------------- launch ----------------
extern "C" void kernel_launch(void* const* d_in, const int* in_sizes, int n_in,
                              void* d_out, int out_size, void* d_ws, size_t ws_size,
                              hipStream_t stream)
{
    const float* q    = (const float*)d_in[0];
    const float* k    = (const float*)d_in[1];
    const float* v    = (const float*)d_in[2];
    const int*   mask = (const int*)  d_in[3];
    const float* Wq   = (const float*)d_in[4];
    const float* Wk   = (const float*)d_in[5];
    const float* Wv   = (const float*)d_in[6];
    const float* Wo   = (const float*)d_in[7];
    const float* bo   = (const float*)d_in[8];
    const float* g1   = (const float*)d_in[9];
    const float* b1   = (const float*)d_in[10];
    const float* g2   = (const float*)d_in[11];
    const float* bt2  = (const float*)d_in[12];
    float* out = (float*)d_out;

    short* ws = (short*)d_ws;
    const size_t WSZ  = (size_t)DMODEL * DMODEL;
    const size_t SLOT = (size_t)R_TOT * DMODEL;
    short* wq  = ws;
    short* wk  = ws + WSZ;
    short* wv  = ws + 2 * WSZ;
    short* wo  = ws + 3 * WSZ;
    short* qb  = ws + 4 * WSZ;
    short* kb  = qb + SLOT;
    short* vb  = kb + SLOT;
    short* qpb = vb + SLOT;
    short* kpb = qpb + SLOT;
    short* vtb = kpb + SLOT;     // vt[b][dmodel][SEQ]
    short* at  = qb;             // qb dead after q-projection
    short* y   = kb;             // kb dead after k-projection
    short* z   = vb;             // vb dead after vt GEMM

    const int nCvtBlocks = (3 * N4B + 4 * N4W) / 256;   // 13312
    cvt_all<<<nCvtBlocks, 256, 0, stream>>>(q, k, v, Wq, Wk, Wv, Wo,
                                            qb, kb, vb, wq, wk, wv, wo);

    // kp pre-scaled by (1/sqrt(512)) * log2(e) for exp2-domain softmax
    const float kscale = 0.06375871530f;

    dim3 gg(DMODEL / GBN, R_TOT / GBM, 1);   // (8, 64)
    gemm_bf16<<<gg, 256, 0, stream>>>(qb, wq, nullptr, qpb, R_TOT, DMODEL, DMODEL, 0, 1.0f, 0, 0, 0);
    gemm_bf16<<<gg, 256, 0, stream>>>(kb, wk, nullptr, kpb, R_TOT, DMODEL, DMODEL, 0, kscale, 0, 0, 0);
    // vt[b] = Wv (512x512) @ v_b^T  -> [DMODEL][SEQ], coalesced transposed V-projection
    dim3 gv(SEQ / GBN, DMODEL / GBM, NB);    // (16, 4, 8)
    gemm_bf16<<<gv, 256, 0, stream>>>(wv, vb, nullptr, vtb, DMODEL, SEQ, DMODEL, 0, 1.0f,
                                      0, (long)SEQ * DMODEL, (long)DMODEL * SEQ);

    attn_mfma4<<<dim3(SEQ / 64, NH, NB), 256, 0, stream>>>(qpb, kpb, vtb, mask, at);

    add_ln_b<<<R_TOT, 256, 0, stream>>>(qpb, at, g1, b1, y, nullptr);

    gemm_bf16<<<gg, 256, 0, stream>>>(y, wo, bo, z, R_TOT, DMODEL, DMODEL, 1, 1.0f, 0, 0, 0);

    add_ln_b<<<R_TOT, 256, 0, stream>>>(y, z, g2, bt2, nullptr, out);
}